// Round 2
// baseline (4322.071 us; speedup 1.0000x reference)
//
#include <hip/hip_runtime.h>

#define TT 16
#define BB 8
#define NNODE 5000
#define EE 80000
#define GS 132              // g row stride (130 used cols, padded for 16B align)
#define MM (BB*NNODE)       // 40000 rows

// ---------------- edge_index dtype detect + normalize ----------------
// int64 data (values < 5000) has every odd 32-bit word == 0; random int32
// indices essentially never do. One thread checks 64 elements.
__global__ void detect_k(const unsigned* __restrict__ raw, int* __restrict__ flag) {
  if (threadIdx.x == 0) {
    int is64 = 1;
    for (int i = 0; i < 64; ++i) if (raw[2 * i + 1] != 0u) { is64 = 0; break; }
    *flag = is64;
  }
}

__global__ void normalize_k(const void* __restrict__ ei, const int* __restrict__ flag,
                            int* __restrict__ es, int* __restrict__ ed) {
  int e = blockIdx.x * 256 + threadIdx.x;
  if (e >= EE) return;
  if (*flag) {
    es[e] = (int)((const long long*)ei)[e];
    ed[e] = (int)((const long long*)ei)[EE + e];
  } else {
    es[e] = ((const int*)ei)[e];
    ed[e] = ((const int*)ei)[EE + e];
  }
}

// ---------------- prep: fold W cols 64..191 + attention dots into Wc[128][GS] ----------------
// Wc[k][c]   = W[k][64+c]  (c<128: z|n columns; cc_r is never used by the GRU)
// Wc[k][128] = sum_f W[k][f]*att_s[f]   (a_s is linear in comb -> fold into GEMM)
// Wc[k][129] = sum_f W[k][f]*att_d[f]
__global__ void prep_w(const float* __restrict__ W, const float* __restrict__ as,
                       const float* __restrict__ ad, float* __restrict__ Wc) {
  int k = threadIdx.x;  // 0..127
  const float* row = W + k * 192;
  float* orow = Wc + k * GS;
  for (int c = 0; c < 128; ++c) orow[c] = row[64 + c];
  float ss = 0.f, sd = 0.f;
  for (int f = 0; f < 192; ++f) { ss = fmaf(row[f], as[f], ss); sd = fmaf(row[f], ad[f], sd); }
  orow[128] = ss; orow[129] = sd;
}

// ---------------- CSR build (edge_index constant across all 32 steps) ----------------
__global__ void init_counts(int* counts) {
  int i = blockIdx.x * 256 + threadIdx.x;
  if (i < NNODE) counts[i] = 1;           // self-loop pre-counted
}

// invalid (src==dst) original edges get e=-inf in the reference -> alpha=0 exactly
// (self-loop guarantees finite segment max) -> drop them from CSR entirely.
__global__ void count_edges(const int* __restrict__ es, const int* __restrict__ ed,
                            int* __restrict__ counts) {
  int e = blockIdx.x * 256 + threadIdx.x;
  if (e >= EE) return;
  int s = es[e], d = ed[e];
  if (s != d) atomicAdd(&counts[d], 1);
}

__global__ void scan_k(const int* __restrict__ counts, int* __restrict__ off,
                       int* __restrict__ cursor) {
  __shared__ int buf[1024];
  __shared__ int carry_s;
  int tid = threadIdx.x;
  if (tid == 0) carry_s = 0;
  __syncthreads();
  for (int base = 0; base < NNODE; base += 1024) {
    int i = base + tid;
    int v = (i < NNODE) ? counts[i] : 0;
    buf[tid] = v;
    __syncthreads();
    for (int o = 1; o < 1024; o <<= 1) {
      int t = (tid >= o) ? buf[tid - o] : 0;
      __syncthreads();
      buf[tid] += t;
      __syncthreads();
    }
    int carry = carry_s;
    int excl = carry + buf[tid] - v;
    if (i < NNODE) { off[i] = excl; cursor[i] = excl; }
    __syncthreads();
    if (tid == 1023) carry_s = carry + buf[1023];
    __syncthreads();
  }
  if (tid == 0) off[NNODE] = carry_s;
}

__global__ void scatter_k(const int* __restrict__ es, const int* __restrict__ ed,
                          int* cursor, int* __restrict__ csr) {
  int idx = blockIdx.x * 256 + threadIdx.x;
  if (idx < EE) {
    int s = es[idx], d = ed[idx];
    if (s != d) { int p = atomicAdd(&cursor[d], 1); csr[p] = s; }
  } else if (idx < EE + NNODE) {
    int n = idx - EE;
    int p = atomicAdd(&cursor[n], 1); csr[p] = n;
  }
}

// ---------------- per-step GEMM: g[row][0..129] = [in(64)|h(64)] @ Wc ----------------
// lane = row (64 rows/block), wave w covers cols w*32..w*32+31; weights are
// wave-uniform -> SGPR broadcast (1 sgpr/VALU inst). comb rows live in LDS with
// XOR-chunk swizzle (ck^(row&7)) so per-lane float4 reads hit the 8-cycle bank floor.
// Attention cols 128/129 are 2 extra SGPR-weight accumulators on waves 0/1.
__global__ __launch_bounds__(256) void gemm_step(
    const float* __restrict__ in, const float* __restrict__ h,
    const float* __restrict__ Wc, float* __restrict__ g)
{
  __shared__ float lds[8320];          // stage: 64x128 swizzled; transpose: 130x64
  float4* lds4 = (float4*)lds;
  const int tid = threadIdx.x;
  const int row0 = blockIdx.x * 64;

  // stage comb = [in | h], swizzled chunks
  {
    int i = tid >> 2, q = tid & 3;     // row i, quarter q (32 floats each)
    const float* srcp = (q < 2) ? in + (size_t)(row0 + i) * 64 + q * 32
                                : h  + (size_t)(row0 + i) * 64 + (q - 2) * 32;
    const float4* s4 = (const float4*)srcp;
#pragma unroll
    for (int j = 0; j < 8; ++j)
      lds4[i * 32 + ((q * 8 + j) ^ (i & 7))] = s4[j];
  }
  __syncthreads();

  const int l = tid & 63;                                    // lane = row
  const int w = __builtin_amdgcn_readfirstlane(tid >> 6);    // force wave-uniform
  const int c0 = w * 32;

  float acc[32];
#pragma unroll
  for (int c = 0; c < 32; ++c) acc[c] = 0.f;
  float accs = 0.f, accd = 0.f;

#pragma unroll 2
  for (int ck = 0; ck < 32; ++ck) {
    float4 c4 = lds4[l * 32 + (ck ^ (l & 7))];
#pragma unroll
    for (int kk = 0; kk < 4; ++kk) {
      int k = ck * 4 + kk;
      const float* wk = Wc + k * GS;                         // uniform -> s_load
      float cv = (kk == 0) ? c4.x : (kk == 1) ? c4.y : (kk == 2) ? c4.z : c4.w;
#pragma unroll
      for (int c = 0; c < 32; ++c)
        acc[c] = fmaf(cv, wk[c0 + c], acc[c]);
      if (w == 0) accs = fmaf(cv, wk[128], accs);
      if (w == 1) accd = fmaf(cv, wk[129], accd);
    }
  }
  __syncthreads();

  // transpose through LDS: lds[c*64 + row]; writes are 2 lanes/bank -> free
#pragma unroll
  for (int c = 0; c < 32; ++c) lds[(c0 + c) * 64 + l] = acc[c];
  if (w == 0) lds[128 * 64 + l] = accs;
  if (w == 1) lds[129 * 64 + l] = accd;
  __syncthreads();

  // coalesced float4 store of g rows
  {
    int r = tid >> 2, q = tid & 3;
    float* grow = g + (size_t)(row0 + r) * GS;
#pragma unroll
    for (int it = 0; it < 8; ++it) {
      int cc = q + it * 4;             // float4 chunk: cols cc*4..cc*4+3
      float4 v;
      v.x = lds[(cc * 4 + 0) * 64 + r];
      v.y = lds[(cc * 4 + 1) * 64 + r];
      v.z = lds[(cc * 4 + 2) * 64 + r];
      v.w = lds[(cc * 4 + 3) * 64 + r];
      *(float4*)(grow + cc * 4) = v;
    }
    if (tid < 128) {
      int rr = tid & 63, c = 128 + (tid >> 6);
      g[(size_t)(row0 + rr) * GS + c] = lds[c * 64 + rr];
    }
  }
}

// ---------------- edge softmax + aggregate + GRU update (fused) ----------------
// wave per (b,node): lanes = 128 channels (2/lane); serial loop over ~17 CSR edges.
__global__ __launch_bounds__(256) void edge_step(
    const float* __restrict__ g, const int* __restrict__ off, const int* __restrict__ csr,
    const float* __restrict__ bias, float* __restrict__ h, float* __restrict__ yout)
{
  int w = threadIdx.x >> 6, l = threadIdx.x & 63;
  int b = blockIdx.x & 7;                       // batch -> XCD affinity (g slab ~2.6MB/batch fits L2)
  int n = (blockIdx.x >> 3) * 4 + w;            // 0..4999
  int base = b * NNODE + n;
  const float* gb = g + (size_t)b * NNODE * GS;
  float ad = g[(size_t)base * GS + 129];
  int s0 = off[n], s1 = off[n + 1];

  // pass A: segment max (lanes strided over edges; deg>=1 via self-loop)
  float m = -1e30f;
  for (int j = s0 + l; j < s1; j += 64) {
    int src = csr[j];
    float e = gb[(size_t)src * GS + 128] + ad;
    e = e > 0.f ? e : 0.2f * e;
    m = fmaxf(m, e);
  }
#pragma unroll
  for (int o = 32; o; o >>= 1) m = fmaxf(m, __shfl_xor(m, o));

  // pass B: weighted aggregate; channel gathers are 2x256B coalesced per edge
  float den = 0.f, a0 = 0.f, a1 = 0.f;
  for (int j = s0; j < s1; ++j) {
    int src = csr[j];
    const float* gr = gb + (size_t)src * GS;
    float e = gr[128] + ad;
    e = e > 0.f ? e : 0.2f * e;
    float al = __expf(e - m);
    den += al;
    a0 = fmaf(al, gr[l], a0);
    a1 = fmaf(al, gr[64 + l], a1);
  }

  // fused GRU pointwise: z = sigmoid(.); n = tanh(.); h' = (1-z)*n + z*h
  float inv = 1.0f / den;
  float zx = fmaf(a0, inv, bias[64 + l]);
  float z = 1.0f / (1.0f + __expf(-zx));
  float nx = fmaf(a1, inv, bias[128 + l]);
  float e2 = __expf(2.0f * nx);
  float nn = 1.0f - 2.0f / (e2 + 1.0f);
  float hp = h[(size_t)base * 64 + l];
  float hn = (1.0f - z) * nn + z * hp;
  h[(size_t)base * 64 + l] = hn;
  yout[(size_t)base * 64 + l] = hn;
}

// ---------------- host ----------------
extern "C" void kernel_launch(void* const* d_in, const int* in_sizes, int n_in,
                              void* d_out, int out_size, void* d_ws, size_t ws_size,
                              hipStream_t stream)
{
  const float* x   = (const float*)d_in[0];
  const void*  ei  = d_in[1];
  const float* W0  = (const float*)d_in[2];
  const float* as0 = (const float*)d_in[3];
  const float* ad0 = (const float*)d_in[4];
  const float* b0  = (const float*)d_in[5];
  const float* W1  = (const float*)d_in[6];
  const float* as1 = (const float*)d_in[7];
  const float* ad1 = (const float*)d_in[8];
  const float* b1  = (const float*)d_in[9];
  float* out = (float*)d_out;

  float* ws  = (float*)d_ws;
  float* Wc0 = ws;                               // 128*GS
  float* Wc1 = Wc0 + 128 * GS;
  float* g   = Wc1 + 128 * GS;                   // MM*GS
  float* h   = g + (size_t)MM * GS;              // MM*64
  int* ib     = (int*)(h + (size_t)MM * 64);
  int* flag   = ib;                              // 16 (padded)
  int* es     = ib + 16;                         // EE
  int* ed     = es + EE;                         // EE
  int* counts = ed + EE;                         // 5008
  int* off    = counts + 5008;                   // 5008
  int* cursor = off + 5008;                      // 5008
  int* csr    = cursor + 5008;                   // EE+NNODE

  detect_k<<<1, 64, 0, stream>>>((const unsigned*)ei, flag);
  normalize_k<<<(EE + 255) / 256, 256, 0, stream>>>(ei, flag, es, ed);
  prep_w<<<1, 128, 0, stream>>>(W0, as0, ad0, Wc0);
  prep_w<<<1, 128, 0, stream>>>(W1, as1, ad1, Wc1);
  init_counts<<<(NNODE + 255) / 256, 256, 0, stream>>>(counts);
  count_edges<<<(EE + 255) / 256, 256, 0, stream>>>(es, ed, counts);
  scan_k<<<1, 1024, 0, stream>>>(counts, off, cursor);
  scatter_k<<<(EE + NNODE + 255) / 256, 256, 0, stream>>>(es, ed, cursor, csr);

  size_t slab = (size_t)MM * 64;

  hipMemsetAsync(h, 0, slab * sizeof(float), stream);
  for (int t = 0; t < TT; ++t) {
    gemm_step<<<625, 256, 0, stream>>>(x + (size_t)t * slab, h, Wc0, g);
    edge_step<<<10000, 256, 0, stream>>>(g, off, csr, b0, h, out + (size_t)t * slab);
  }

  hipMemsetAsync(h, 0, slab * sizeof(float), stream);
  float* out1 = out + (size_t)TT * slab;
  for (int t = 0; t < TT; ++t) {
    gemm_step<<<625, 256, 0, stream>>>(out + (size_t)t * slab, h, Wc1, g);
    edge_step<<<10000, 256, 0, stream>>>(g, off, csr, b1, h, out1 + (size_t)t * slab);
  }
}

// Round 3
// 3484.282 us; speedup vs baseline: 1.2404x; 1.2404x over previous
//
#include <hip/hip_runtime.h>

#define TT 16
#define BB 8
#define NNODE 5000
#define EE 80000
#define GS 132              // g row stride (130 used cols, padded for 16B align)
#define MM (BB*NNODE)       // 40000 rows

// ---------------- edge_index dtype detect + normalize ----------------
__global__ void detect_k(const unsigned* __restrict__ raw, int* __restrict__ flag) {
  if (threadIdx.x == 0) {
    int is64 = 1;
    for (int i = 0; i < 64; ++i) if (raw[2 * i + 1] != 0u) { is64 = 0; break; }
    *flag = is64;
  }
}

__global__ void normalize_k(const void* __restrict__ ei, const int* __restrict__ flag,
                            int* __restrict__ es, int* __restrict__ ed) {
  int e = blockIdx.x * 256 + threadIdx.x;
  if (e >= EE) return;
  if (*flag) {
    es[e] = (int)((const long long*)ei)[e];
    ed[e] = (int)((const long long*)ei)[EE + e];
  } else {
    es[e] = ((const int*)ei)[e];
    ed[e] = ((const int*)ei)[EE + e];
  }
}

// ---------------- prep: fold W cols 64..191 + attention dots into Wc[128][GS] ----------------
// Wc[k][c]   = W[k][64+c]  (c<128: z|n cols; cc_r never used by the GRU)
// Wc[k][128] = sum_f W[k][f]*att_s[f]   (a_s linear in comb -> fold into GEMM)
// Wc[k][129] = sum_f W[k][f]*att_d[f]
__global__ void prep_w(const float* __restrict__ W, const float* __restrict__ as,
                       const float* __restrict__ ad, float* __restrict__ Wc) {
  int k = threadIdx.x;  // 0..127
  const float* row = W + k * 192;
  float* orow = Wc + k * GS;
  for (int c = 0; c < 128; ++c) orow[c] = row[64 + c];
  float ss = 0.f, sd = 0.f;
  for (int f = 0; f < 192; ++f) { ss = fmaf(row[f], as[f], ss); sd = fmaf(row[f], ad[f], sd); }
  orow[128] = ss; orow[129] = sd;
}

// ---------------- CSR build (edge_index constant across all 32 steps) ----------------
__global__ void init_counts(int* counts) {
  int i = blockIdx.x * 256 + threadIdx.x;
  if (i < NNODE) counts[i] = 1;           // self-loop pre-counted
}

__global__ void count_edges(const int* __restrict__ es, const int* __restrict__ ed,
                            int* __restrict__ counts) {
  int e = blockIdx.x * 256 + threadIdx.x;
  if (e >= EE) return;
  int s = es[e], d = ed[e];
  if (s != d) atomicAdd(&counts[d], 1);   // src==dst originals get alpha=0 exactly -> drop
}

__global__ void scan_k(const int* __restrict__ counts, int* __restrict__ off,
                       int* __restrict__ cursor) {
  __shared__ int buf[1024];
  __shared__ int carry_s;
  int tid = threadIdx.x;
  if (tid == 0) carry_s = 0;
  __syncthreads();
  for (int base = 0; base < NNODE; base += 1024) {
    int i = base + tid;
    int v = (i < NNODE) ? counts[i] : 0;
    buf[tid] = v;
    __syncthreads();
    for (int o = 1; o < 1024; o <<= 1) {
      int t = (tid >= o) ? buf[tid - o] : 0;
      __syncthreads();
      buf[tid] += t;
      __syncthreads();
    }
    int carry = carry_s;
    int excl = carry + buf[tid] - v;
    if (i < NNODE) { off[i] = excl; cursor[i] = excl; }
    __syncthreads();
    if (tid == 1023) carry_s = carry + buf[1023];
    __syncthreads();
  }
  if (tid == 0) off[NNODE] = carry_s;
}

__global__ void scatter_k(const int* __restrict__ es, const int* __restrict__ ed,
                          int* cursor, int* __restrict__ csr) {
  int idx = blockIdx.x * 256 + threadIdx.x;
  if (idx < EE) {
    int s = es[idx], d = ed[idx];
    if (s != d) { int p = atomicAdd(&cursor[d], 1); csr[p] = s; }
  } else if (idx < EE + NNODE) {
    int n = idx - EE;
    int p = atomicAdd(&cursor[n], 1); csr[p] = n;
  }
}

// ---------------- per-step GEMM: g[row][0..129] = [in(64)|h(64)] @ Wc ----------------
// 128 thr / 2 waves per block, 64 rows, wave w = cols w*64..w*64+63 (+ att col 128+w).
// Lane (rg,cg) owns an 8x8 register tile. comb is staged k-major in LDS (combT[k][row])
// so the comb fragment is 2 per-lane ds_read_b128 (2-way bank alias = free); weights
// stream from global (L1/L2-resident 67KB) as 2 dwordx4 per k. 72 FMA vs 24 LDS cyc
// per k per wave -> VALU-bound by construction.
// Grid: blockIdx = b + 8*j (b=batch) so each batch's g slab stays on one XCD's L2.
__global__ __launch_bounds__(128) void gemm_step(
    const float* __restrict__ in, const float* __restrict__ h,
    const float* __restrict__ Wc, float* __restrict__ g)
{
  __shared__ float combT[128 * 64];     // [k][row], 32KB
  const int tid = threadIdx.x;
  const int b = blockIdx.x & 7;
  const int j = blockIdx.x >> 3;        // 0..78
  const int row0 = j * 64;              // within batch
  const int nrows = (NNODE - row0) < 64 ? (NNODE - row0) : 64;
  const size_t gbase = (size_t)b * NNODE;

  // stage: thread t -> row r = t&63, source q = t>>6 (0: in k0..63, 1: h k64..127)
  {
    int r = tid & 63, q = tid >> 6;
    int rr = (r < nrows) ? r : 0;       // clamp (last block of batch 7 would run OOB)
    const float* src = (q ? h : in) + (gbase + row0 + rr) * 64;
#pragma unroll
    for (int c4 = 0; c4 < 16; ++c4) {
      float4 v = ((const float4*)src)[c4];
      int k = q * 64 + c4 * 4;
      combT[(k + 0) * 64 + r] = v.x;
      combT[(k + 1) * 64 + r] = v.y;
      combT[(k + 2) * 64 + r] = v.z;
      combT[(k + 3) * 64 + r] = v.w;
    }
  }
  __syncthreads();

  const int l = tid & 63;
  const int w = __builtin_amdgcn_readfirstlane(tid >> 6);
  const int rg = l >> 3, cg = l & 7;
  const int c0 = w * 64 + cg * 8;

  float acc[8][8];
#pragma unroll
  for (int i = 0; i < 8; ++i)
#pragma unroll
    for (int c = 0; c < 8; ++c) acc[i][c] = 0.f;
  float atta[8];
#pragma unroll
  for (int i = 0; i < 8; ++i) atta[i] = 0.f;

#pragma unroll 2
  for (int k = 0; k < 128; ++k) {
    float4 ca = *(float4*)&combT[k * 64 + rg * 8];
    float4 cb = *(float4*)&combT[k * 64 + rg * 8 + 4];
    float4 wa = *(const float4*)&Wc[k * GS + c0];
    float4 wb = *(const float4*)&Wc[k * GS + c0 + 4];
    float wat = Wc[k * GS + 128 + w];   // uniform addr -> scalar/broadcast
    float cv[8] = {ca.x, ca.y, ca.z, ca.w, cb.x, cb.y, cb.z, cb.w};
    float wv[8] = {wa.x, wa.y, wa.z, wa.w, wb.x, wb.y, wb.z, wb.w};
#pragma unroll
    for (int i = 0; i < 8; ++i) {
#pragma unroll
      for (int c = 0; c < 8; ++c) acc[i][c] = fmaf(cv[i], wv[c], acc[i][c]);
      atta[i] = fmaf(cv[i], wat, atta[i]);
    }
  }

  // epilogue: direct stores (8 rows x 2 float4 per lane); att col by cg==0 lanes
#pragma unroll
  for (int i = 0; i < 8; ++i) {
    int r = rg * 8 + i;
    if (r < nrows) {
      float* grow = g + (gbase + row0 + r) * GS;
      *(float4*)(grow + c0) = make_float4(acc[i][0], acc[i][1], acc[i][2], acc[i][3]);
      *(float4*)(grow + c0 + 4) = make_float4(acc[i][4], acc[i][5], acc[i][6], acc[i][7]);
      if (cg == 0) grow[128 + w] = atta[i];
    }
  }
}

// ---------------- edge softmax + aggregate + GRU update (fused) ----------------
// wave per (b,node): lanes = 128 channels (2/lane); serial loop over ~17 CSR edges.
__global__ __launch_bounds__(256) void edge_step(
    const float* __restrict__ g, const int* __restrict__ off, const int* __restrict__ csr,
    const float* __restrict__ bias, float* __restrict__ h, float* __restrict__ yout)
{
  int w = threadIdx.x >> 6, l = threadIdx.x & 63;
  int b = blockIdx.x & 7;                       // batch -> XCD affinity
  int n = (blockIdx.x >> 3) * 4 + w;            // 0..4999
  int base = b * NNODE + n;
  const float* gb = g + (size_t)b * NNODE * GS;
  float ad = g[(size_t)base * GS + 129];
  int s0 = off[n], s1 = off[n + 1];

  // pass A: segment max (lanes strided over edges; deg>=1 via self-loop)
  float m = -1e30f;
  for (int jj = s0 + l; jj < s1; jj += 64) {
    int src = csr[jj];
    float e = gb[(size_t)src * GS + 128] + ad;
    e = e > 0.f ? e : 0.2f * e;
    m = fmaxf(m, e);
  }
#pragma unroll
  for (int o = 32; o; o >>= 1) m = fmaxf(m, __shfl_xor(m, o));

  // pass B: weighted aggregate; channel gathers are 2x256B coalesced per edge
  float den = 0.f, a0 = 0.f, a1 = 0.f;
  for (int jj = s0; jj < s1; ++jj) {
    int src = csr[jj];
    const float* gr = gb + (size_t)src * GS;
    float e = gr[128] + ad;
    e = e > 0.f ? e : 0.2f * e;
    float al = __expf(e - m);
    den += al;
    a0 = fmaf(al, gr[l], a0);
    a1 = fmaf(al, gr[64 + l], a1);
  }

  // fused GRU pointwise: z = sigmoid(.); n = tanh(.); h' = (1-z)*n + z*h
  float inv = 1.0f / den;
  float zx = fmaf(a0, inv, bias[64 + l]);
  float z = 1.0f / (1.0f + __expf(-zx));
  float nx = fmaf(a1, inv, bias[128 + l]);
  float e2 = __expf(2.0f * nx);
  float nn = 1.0f - 2.0f / (e2 + 1.0f);
  float hp = h[(size_t)base * 64 + l];
  float hn = (1.0f - z) * nn + z * hp;
  h[(size_t)base * 64 + l] = hn;
  yout[(size_t)base * 64 + l] = hn;
}

// ---------------- host ----------------
extern "C" void kernel_launch(void* const* d_in, const int* in_sizes, int n_in,
                              void* d_out, int out_size, void* d_ws, size_t ws_size,
                              hipStream_t stream)
{
  const float* x   = (const float*)d_in[0];
  const void*  ei  = d_in[1];
  const float* W0  = (const float*)d_in[2];
  const float* as0 = (const float*)d_in[3];
  const float* ad0 = (const float*)d_in[4];
  const float* b0  = (const float*)d_in[5];
  const float* W1  = (const float*)d_in[6];
  const float* as1 = (const float*)d_in[7];
  const float* ad1 = (const float*)d_in[8];
  const float* b1  = (const float*)d_in[9];
  float* out = (float*)d_out;

  float* ws  = (float*)d_ws;
  float* Wc0 = ws;                               // 128*GS
  float* Wc1 = Wc0 + 128 * GS;
  float* g   = Wc1 + 128 * GS;                   // MM*GS
  float* h   = g + (size_t)MM * GS;              // MM*64
  int* ib     = (int*)(h + (size_t)MM * 64);
  int* flag   = ib;                              // 16 (padded)
  int* es     = ib + 16;                         // EE
  int* ed     = es + EE;                         // EE
  int* counts = ed + EE;                         // 5008
  int* off    = counts + 5008;                   // 5008
  int* cursor = off + 5008;                      // 5008
  int* csr    = cursor + 5008;                   // EE+NNODE

  detect_k<<<1, 64, 0, stream>>>((const unsigned*)ei, flag);
  normalize_k<<<(EE + 255) / 256, 256, 0, stream>>>(ei, flag, es, ed);
  prep_w<<<1, 128, 0, stream>>>(W0, as0, ad0, Wc0);
  prep_w<<<1, 128, 0, stream>>>(W1, as1, ad1, Wc1);
  init_counts<<<(NNODE + 255) / 256, 256, 0, stream>>>(counts);
  count_edges<<<(EE + 255) / 256, 256, 0, stream>>>(es, ed, counts);
  scan_k<<<1, 1024, 0, stream>>>(counts, off, cursor);
  scatter_k<<<(EE + NNODE + 255) / 256, 256, 0, stream>>>(es, ed, cursor, csr);

  size_t slab = (size_t)MM * 64;

  hipMemsetAsync(h, 0, slab * sizeof(float), stream);
  for (int t = 0; t < TT; ++t) {
    gemm_step<<<632, 128, 0, stream>>>(x + (size_t)t * slab, h, Wc0, g);
    edge_step<<<10000, 256, 0, stream>>>(g, off, csr, b0, h, out + (size_t)t * slab);
  }

  hipMemsetAsync(h, 0, slab * sizeof(float), stream);
  float* out1 = out + (size_t)TT * slab;
  for (int t = 0; t < TT; ++t) {
    gemm_step<<<632, 128, 0, stream>>>(out + (size_t)t * slab, h, Wc1, g);
    edge_step<<<10000, 256, 0, stream>>>(g, off, csr, b1, h, out1 + (size_t)t * slab);
  }
}

// Round 7
// 2918.530 us; speedup vs baseline: 1.4809x; 1.1938x over previous
//
#include <hip/hip_runtime.h>

#define TT 16
#define BB 8
#define NNODE 5000
#define EE 80000
#define MM (BB*NNODE)       // 40000 rows

// ---------------- edge_index dtype detect + normalize ----------------
__global__ void detect_k(const unsigned* __restrict__ raw, int* __restrict__ flag) {
  if (threadIdx.x == 0) {
    int is64 = 1;
    for (int i = 0; i < 64; ++i) if (raw[2 * i + 1] != 0u) { is64 = 0; break; }
    *flag = is64;
  }
}

__global__ void normalize_k(const void* __restrict__ ei, const int* __restrict__ flag,
                            int* __restrict__ es, int* __restrict__ ed) {
  int e = blockIdx.x * 256 + threadIdx.x;
  if (e >= EE) return;
  if (*flag) {
    es[e] = (int)((const long long*)ei)[e];
    ed[e] = (int)((const long long*)ei)[EE + e];
  } else {
    es[e] = ((const int*)ei)[e];
    ed[e] = ((const int*)ei)[EE + e];
  }
}

// ---------------- prep: Wc[k][128] = W[k][64..191]; Was/Wad[k] = W row . att ----------------
__global__ void prep_w(const float* __restrict__ W, const float* __restrict__ as,
                       const float* __restrict__ ad, float* __restrict__ Wc,
                       float* __restrict__ Was, float* __restrict__ Wad) {
  int k = threadIdx.x;  // 0..127
  const float* row = W + k * 192;
  float* orow = Wc + k * 128;
  for (int c = 0; c < 128; ++c) orow[c] = row[64 + c];
  float ss = 0.f, sd = 0.f;
  for (int f = 0; f < 192; ++f) { ss = fmaf(row[f], as[f], ss); sd = fmaf(row[f], ad[f], sd); }
  Was[k] = ss; Wad[k] = sd;
}

// ---------------- CSR build (edge_index constant across all 32 steps) ----------------
__global__ void init_counts(int* counts) {
  int i = blockIdx.x * 256 + threadIdx.x;
  if (i < NNODE) counts[i] = 1;           // self-loop pre-counted
}

__global__ void count_edges(const int* __restrict__ es, const int* __restrict__ ed,
                            int* __restrict__ counts) {
  int e = blockIdx.x * 256 + threadIdx.x;
  if (e >= EE) return;
  int s = es[e], d = ed[e];
  if (s != d) atomicAdd(&counts[d], 1);   // src==dst originals get alpha=0 exactly -> drop
}

__global__ void scan_k(const int* __restrict__ counts, int* __restrict__ off,
                       int* __restrict__ cursor) {
  __shared__ int buf[1024];
  __shared__ int carry_s;
  int tid = threadIdx.x;
  if (tid == 0) carry_s = 0;
  __syncthreads();
  for (int base = 0; base < NNODE; base += 1024) {
    int i = base + tid;
    int v = (i < NNODE) ? counts[i] : 0;
    buf[tid] = v;
    __syncthreads();
    for (int o = 1; o < 1024; o <<= 1) {
      int t = (tid >= o) ? buf[tid - o] : 0;
      __syncthreads();
      buf[tid] += t;
      __syncthreads();
    }
    int carry = carry_s;
    int excl = carry + buf[tid] - v;
    if (i < NNODE) { off[i] = excl; cursor[i] = excl; }
    __syncthreads();
    if (tid == 1023) carry_s = carry + buf[1023];
    __syncthreads();
  }
  if (tid == 0) off[NNODE] = carry_s;
}

__global__ void scatter_k(const int* __restrict__ es, const int* __restrict__ ed,
                          int* cursor, int* __restrict__ csr) {
  int idx = blockIdx.x * 256 + threadIdx.x;
  if (idx < EE) {
    int s = es[idx], d = ed[idx];
    if (s != d) { int p = atomicAdd(&cursor[d], 1); csr[p] = s; }
  } else if (idx < EE + NNODE) {
    int n = idx - EE;
    int p = atomicAdd(&cursor[n], 1); csr[p] = n;
  }
}

// ---------------- per-step GEMM ----------------
// 256 thr / 4 waves; block = 32 rows x 128 cols (+att). Wave (wrow,wcol); lane owns
// 2 rows x 8 cols. comb staged k-major in LDS (ds_read_b64/lane); weights stream from
// global (64KB, L1/L2-hot, shared by all blocks). 18 FMA : 1 LDS inst per k -> VALU-bound.
// 5024 waves (~4.9/SIMD) fixes the old 1264-wave makespan imbalance.
__global__ __launch_bounds__(256) void gemm_step(
    const float* __restrict__ in, const float* __restrict__ h,
    const float* __restrict__ Wc, const float* __restrict__ Was, const float* __restrict__ Wad,
    float* __restrict__ g, float* __restrict__ LS, float* __restrict__ LD)
{
  __shared__ float combT[128 * 32];     // [k][row], 16KB
  const int tid = threadIdx.x;
  const int b = blockIdx.x & 7;         // batch -> XCD affinity
  const int j = blockIdx.x >> 3;        // 0..156
  const int row0 = j * 32;
  const int nrows = (NNODE - row0) < 32 ? (NNODE - row0) : 32;
  const size_t gbase = (size_t)b * NNODE;

  { // stage: thread t -> row r=t&31, chunk q=t>>5 (16 k each)
    int r = tid & 31, q = tid >> 5;
    int rr = (r < nrows) ? r : 0;
    const float* src = (q < 4) ? in + (gbase + row0 + rr) * 64 + q * 16
                               : h  + (gbase + row0 + rr) * 64 + (q - 4) * 16;
#pragma unroll
    for (int c4 = 0; c4 < 4; ++c4) {
      float4 v = ((const float4*)src)[c4];
      int k = q * 16 + c4 * 4;
      combT[(k + 0) * 32 + r] = v.x;
      combT[(k + 1) * 32 + r] = v.y;
      combT[(k + 2) * 32 + r] = v.z;
      combT[(k + 3) * 32 + r] = v.w;
    }
  }
  __syncthreads();

  const int l = tid & 63;
  const int w = __builtin_amdgcn_readfirstlane(tid >> 6);
  const int wrow = w >> 1, wcol = w & 1;
  const int r0 = wrow * 16 + (l >> 3) * 2;      // 2 rows
  const int c0 = wcol * 64 + (l & 7) * 8;       // 8 cols
  const float* Wat = wcol ? Wad : Was;

  float acc[2][8];
#pragma unroll
  for (int i = 0; i < 2; ++i)
#pragma unroll
    for (int c = 0; c < 8; ++c) acc[i][c] = 0.f;
  float atta[2] = {0.f, 0.f};

#pragma unroll 4
  for (int k = 0; k < 128; ++k) {
    float2 cr = *(const float2*)&combT[k * 32 + r0];
    float4 wa = *(const float4*)&Wc[k * 128 + c0];
    float4 wb = *(const float4*)&Wc[k * 128 + c0 + 4];
    float wat = Wat[k];
    float wv[8] = {wa.x, wa.y, wa.z, wa.w, wb.x, wb.y, wb.z, wb.w};
#pragma unroll
    for (int c = 0; c < 8; ++c) {
      acc[0][c] = fmaf(cr.x, wv[c], acc[0][c]);
      acc[1][c] = fmaf(cr.y, wv[c], acc[1][c]);
    }
    atta[0] = fmaf(cr.x, wat, atta[0]);
    atta[1] = fmaf(cr.y, wat, atta[1]);
  }

#pragma unroll
  for (int i = 0; i < 2; ++i) {
    int r = r0 + i;
    if (r < nrows) {
      float* grow = g + (gbase + row0 + r) * 128;
      *(float4*)(grow + c0)     = make_float4(acc[i][0], acc[i][1], acc[i][2], acc[i][3]);
      *(float4*)(grow + c0 + 4) = make_float4(acc[i][4], acc[i][5], acc[i][6], acc[i][7]);
      if ((l & 7) == 0) (wcol ? LD : LS)[gbase + row0 + r] = atta[i];
    }
  }
}

// ---------------- edge softmax + aggregate + GRU update (fused) ----------------
// wave per (b,node), lane = channel pair {l, 64+l}. g rows are 512B-aligned (4 lines
// per edge); logits in compact LS/LD (L2-hot). Edge loop software-pipelined 4-wide
// with clamped indices + masked alpha -> 1 exposed latency per 4 edges.
__global__ __launch_bounds__(256) void edge_step(
    const float* __restrict__ g, const float* __restrict__ LS, const float* __restrict__ LD,
    const int* __restrict__ off, const int* __restrict__ csr,
    const float* __restrict__ bias, float* __restrict__ h, float* __restrict__ yout)
{
  int w = threadIdx.x >> 6, l = threadIdx.x & 63;
  int b = blockIdx.x & 7;                       // batch -> XCD affinity
  int n = (blockIdx.x >> 3) * 4 + w;            // 0..4999
  int base = b * NNODE + n;
  const float* gb  = g  + (size_t)b * NNODE * 128;
  const float* LSb = LS + (size_t)b * NNODE;
  float ad = LD[base];
  size_t hidx = (size_t)base * 64 + l;
  float hp = h[hidx];                           // issue early; consumed only in epilogue
  int s0 = off[n], s1 = off[n + 1];

  // pass A: max of a_s over edges; LR applied once (exact, LR monotone)
  float ms = -1e30f;
  for (int jj = s0 + l; jj < s1; jj += 64) ms = fmaxf(ms, LSb[csr[jj]]);
#pragma unroll
  for (int o = 32; o; o >>= 1) ms = fmaxf(ms, __shfl_xor(ms, o));
  float me = ms + ad;
  float m = me > 0.f ? me : 0.2f * me;

  // pass B: 4-wide pipelined aggregate
  float den = 0.f, a0 = 0.f, a1 = 0.f;
  int last = s1 - 1;
  for (int jj = s0; jj < s1; jj += 4) {
    int i1 = jj + 1 > last ? last : jj + 1;
    int i2 = jj + 2 > last ? last : jj + 2;
    int i3 = jj + 3 > last ? last : jj + 3;
    int sA = csr[jj], sB = csr[i1], sC = csr[i2], sD = csr[i3];
    float lsA = LSb[sA], lsB = LSb[sB], lsC = LSb[sC], lsD = LSb[sD];
    const float* gA = gb + (size_t)sA * 128;
    const float* gB = gb + (size_t)sB * 128;
    const float* gC = gb + (size_t)sC * 128;
    const float* gD = gb + (size_t)sD * 128;
    float zA = gA[l], nA = gA[64 + l];
    float zB = gB[l], nB = gB[64 + l];
    float zC = gC[l], nC = gC[64 + l];
    float zD = gD[l], nD = gD[64 + l];
    float eA = lsA + ad; eA = eA > 0.f ? eA : 0.2f * eA;
    float eB = lsB + ad; eB = eB > 0.f ? eB : 0.2f * eB;
    float eC = lsC + ad; eC = eC > 0.f ? eC : 0.2f * eC;
    float eD = lsD + ad; eD = eD > 0.f ? eD : 0.2f * eD;
    float alA = __expf(eA - m);
    float alB = (jj + 1 <= last) ? __expf(eB - m) : 0.f;
    float alC = (jj + 2 <= last) ? __expf(eC - m) : 0.f;
    float alD = (jj + 3 <= last) ? __expf(eD - m) : 0.f;
    den += (alA + alB) + (alC + alD);
    a0 = fmaf(alA, zA, a0); a0 = fmaf(alB, zB, a0);
    a0 = fmaf(alC, zC, a0); a0 = fmaf(alD, zD, a0);
    a1 = fmaf(alA, nA, a1); a1 = fmaf(alB, nB, a1);
    a1 = fmaf(alC, nC, a1); a1 = fmaf(alD, nD, a1);
  }

  // fused GRU pointwise
  float inv = 1.0f / den;
  float zx = fmaf(a0, inv, bias[64 + l]);
  float z = 1.0f / (1.0f + __expf(-zx));
  float nx = fmaf(a1, inv, bias[128 + l]);
  float e2 = __expf(2.0f * nx);
  float nn = 1.0f - 2.0f / (e2 + 1.0f);
  float hn = (1.0f - z) * nn + z * hp;
  h[hidx] = hn;
  yout[hidx] = hn;
}

// ---------------- host ----------------
extern "C" void kernel_launch(void* const* d_in, const int* in_sizes, int n_in,
                              void* d_out, int out_size, void* d_ws, size_t ws_size,
                              hipStream_t stream)
{
  const float* x   = (const float*)d_in[0];
  const void*  ei  = d_in[1];
  const float* W0  = (const float*)d_in[2];
  const float* as0 = (const float*)d_in[3];
  const float* ad0 = (const float*)d_in[4];
  const float* b0  = (const float*)d_in[5];
  const float* W1  = (const float*)d_in[6];
  const float* as1 = (const float*)d_in[7];
  const float* ad1 = (const float*)d_in[8];
  const float* b1  = (const float*)d_in[9];
  float* out = (float*)d_out;

  float* ws   = (float*)d_ws;
  float* Wc0  = ws;                              // 128*128
  float* Was0 = Wc0 + 128 * 128;                 // 128
  float* Wad0 = Was0 + 128;                      // 128
  float* Wc1  = Wad0 + 128;
  float* Was1 = Wc1 + 128 * 128;
  float* Wad1 = Was1 + 128;
  float* g    = Wad1 + 128;                      // MM*128 (512B-aligned rows)
  float* LS   = g + (size_t)MM * 128;            // MM
  float* LD   = LS + MM;                         // MM
  float* h    = LD + MM;                         // MM*64
  int* ib     = (int*)(h + (size_t)MM * 64);
  int* flag   = ib;                              // 16
  int* es     = ib + 16;                         // EE
  int* ed     = es + EE;                         // EE
  int* counts = ed + EE;                         // 5008
  int* off    = counts + 5008;                   // 5008
  int* cursor = off + 5008;                      // 5008
  int* csr    = cursor + 5008;                   // EE+NNODE

  detect_k<<<1, 64, 0, stream>>>((const unsigned*)ei, flag);
  normalize_k<<<(EE + 255) / 256, 256, 0, stream>>>(ei, flag, es, ed);
  prep_w<<<1, 128, 0, stream>>>(W0, as0, ad0, Wc0, Was0, Wad0);
  prep_w<<<1, 128, 0, stream>>>(W1, as1, ad1, Wc1, Was1, Wad1);
  init_counts<<<(NNODE + 255) / 256, 256, 0, stream>>>(counts);
  count_edges<<<(EE + 255) / 256, 256, 0, stream>>>(es, ed, counts);
  scan_k<<<1, 1024, 0, stream>>>(counts, off, cursor);
  scatter_k<<<(EE + NNODE + 255) / 256, 256, 0, stream>>>(es, ed, cursor, csr);

  size_t slab = (size_t)MM * 64;
  const int GB = 157 * 8;                        // gemm blocks: 32 rows each

  hipMemsetAsync(h, 0, slab * sizeof(float), stream);
  for (int t = 0; t < TT; ++t) {
    gemm_step<<<GB, 256, 0, stream>>>(x + (size_t)t * slab, h, Wc0, Was0, Wad0, g, LS, LD);
    edge_step<<<10000, 256, 0, stream>>>(g, LS, LD, off, csr, b0, h, out + (size_t)t * slab);
  }

  hipMemsetAsync(h, 0, slab * sizeof(float), stream);
  float* out1 = out + (size_t)TT * slab;
  for (int t = 0; t < TT; ++t) {
    gemm_step<<<GB, 256, 0, stream>>>(out + (size_t)t * slab, h, Wc1, Was1, Wad1, g, LS, LD);
    edge_step<<<10000, 256, 0, stream>>>(g, LS, LD, off, csr, b1, h, out1 + (size_t)t * slab);
  }
}

// Round 10
// 2333.846 us; speedup vs baseline: 1.8519x; 1.2505x over previous
//
#include <hip/hip_runtime.h>

#define TT 16
#define BB 8
#define NNODE 5000
#define EE 80000
#define MM (BB*NNODE)       // 40000 rows

// ---------------- edge_index dtype detect + normalize ----------------
__global__ void detect_k(const unsigned* __restrict__ raw, int* __restrict__ flag) {
  if (threadIdx.x == 0) {
    int is64 = 1;
    for (int i = 0; i < 64; ++i) if (raw[2 * i + 1] != 0u) { is64 = 0; break; }
    *flag = is64;
  }
}

__global__ void normalize_k(const void* __restrict__ ei, const int* __restrict__ flag,
                            int* __restrict__ es, int* __restrict__ ed) {
  int e = blockIdx.x * 256 + threadIdx.x;
  if (e >= EE) return;
  if (*flag) {
    es[e] = (int)((const long long*)ei)[e];
    ed[e] = (int)((const long long*)ei)[EE + e];
  } else {
    es[e] = ((const int*)ei)[e];
    ed[e] = ((const int*)ei)[EE + e];
  }
}

// ---------------- prep: Wc[k][128] = W[k][64..191]; Was/Wad[k] = W row . att ----------------
__global__ void prep_w(const float* __restrict__ W, const float* __restrict__ as,
                       const float* __restrict__ ad, float* __restrict__ Wc,
                       float* __restrict__ Was, float* __restrict__ Wad) {
  int k = threadIdx.x;  // 0..127
  const float* row = W + k * 192;
  float* orow = Wc + k * 128;
  for (int c = 0; c < 128; ++c) orow[c] = row[64 + c];
  float ss = 0.f, sd = 0.f;
  for (int f = 0; f < 192; ++f) { ss = fmaf(row[f], as[f], ss); sd = fmaf(row[f], ad[f], sd); }
  Was[k] = ss; Wad[k] = sd;
}

// ---------------- CSR build (edge_index constant across all 32 steps) ----------------
__global__ void init_counts(int* counts) {
  int i = blockIdx.x * 256 + threadIdx.x;
  if (i < NNODE) counts[i] = 1;           // self-loop pre-counted
}

__global__ void count_edges(const int* __restrict__ es, const int* __restrict__ ed,
                            int* __restrict__ counts) {
  int e = blockIdx.x * 256 + threadIdx.x;
  if (e >= EE) return;
  int s = es[e], d = ed[e];
  if (s != d) atomicAdd(&counts[d], 1);   // src==dst originals get alpha=0 exactly -> drop
}

__global__ void scan_k(const int* __restrict__ counts, int* __restrict__ off,
                       int* __restrict__ cursor) {
  __shared__ int buf[1024];
  __shared__ int carry_s;
  int tid = threadIdx.x;
  if (tid == 0) carry_s = 0;
  __syncthreads();
  for (int base = 0; base < NNODE; base += 1024) {
    int i = base + tid;
    int v = (i < NNODE) ? counts[i] : 0;
    buf[tid] = v;
    __syncthreads();
    for (int o = 1; o < 1024; o <<= 1) {
      int t = (tid >= o) ? buf[tid - o] : 0;
      __syncthreads();
      buf[tid] += t;
      __syncthreads();
    }
    int carry = carry_s;
    int excl = carry + buf[tid] - v;
    if (i < NNODE) { off[i] = excl; cursor[i] = excl; }
    __syncthreads();
    if (tid == 1023) carry_s = carry + buf[1023];
    __syncthreads();
  }
  if (tid == 0) off[NNODE] = carry_s;
}

__global__ void scatter_k(const int* __restrict__ es, const int* __restrict__ ed,
                          int* cursor, int* __restrict__ csr) {
  int idx = blockIdx.x * 256 + threadIdx.x;
  if (idx < EE) {
    int s = es[idx], d = ed[idx];
    if (s != d) { int p = atomicAdd(&cursor[d], 1); csr[p] = s; }
  } else if (idx < EE + NNODE) {
    int n = idx - EE;
    int p = atomicAdd(&cursor[n], 1); csr[p] = n;
  }
}

// ---------------- per-step GEMM ----------------
// 512 thr / 8 waves; block = 64 rows x 128 cols. lane = row; wave w = cols w*16..+15.
// Weights are wave-uniform -> scalar-cache broadcast (64KB per block exactly; 40MB/step
// L2 traffic, vs 1.26GB/step for per-lane streaming). comb read per-lane from
// combT[k][row] (contiguous, conflict-free). 16 FMA/k/wave, acc[16] -> ~30 VGPR,
// full occupancy; 5056 waves ~ 4.9/SIMD.
__global__ __launch_bounds__(512) void gemm_step(
    const float* __restrict__ in, const float* __restrict__ h,
    const float* __restrict__ Wc, const float* __restrict__ Was, const float* __restrict__ Wad,
    float* __restrict__ g, float* __restrict__ LS, float* __restrict__ LD)
{
  __shared__ float combT[128 * 64];     // [k][row], 32KB
  const int tid = threadIdx.x;
  const int b = blockIdx.x & 7;         // batch -> XCD affinity
  const int j = blockIdx.x >> 3;        // 0..78
  const int row0 = j * 64;
  const int nrows = (NNODE - row0) < 64 ? (NNODE - row0) : 64;
  const size_t gbase = (size_t)b * NNODE;

  { // stage: thread t -> row r=t&63, chunk q=t>>6 (16 k each)
    int r = tid & 63, q = tid >> 6;
    int rr = (r < nrows) ? r : 0;
    const float* src = (q < 4) ? in + (gbase + row0 + rr) * 64 + q * 16
                               : h  + (gbase + row0 + rr) * 64 + (q - 4) * 16;
#pragma unroll
    for (int c4 = 0; c4 < 4; ++c4) {
      float4 v = ((const float4*)src)[c4];
      int k = q * 16 + c4 * 4;
      combT[(k + 0) * 64 + r] = v.x;
      combT[(k + 1) * 64 + r] = v.y;
      combT[(k + 2) * 64 + r] = v.z;
      combT[(k + 3) * 64 + r] = v.w;
    }
  }
  __syncthreads();

  const int l = tid & 63;                                   // lane = row
  const int w = __builtin_amdgcn_readfirstlane(tid >> 6);   // wave-uniform 0..7
  const int c0 = w * 16;

  float acc[16];
#pragma unroll
  for (int c = 0; c < 16; ++c) acc[c] = 0.f;
  float atta = 0.f;
  const float* Wat = (w == 0) ? Was : Wad;   // used only by waves 0/1

#pragma unroll 4
  for (int k = 0; k < 128; ++k) {
    float cv = combT[k * 64 + l];
    const float* wk = Wc + k * 128 + c0;     // uniform address -> s_load broadcast
#pragma unroll
    for (int c = 0; c < 16; ++c) acc[c] = fmaf(cv, wk[c], acc[c]);
    if (w < 2) atta = fmaf(cv, Wat[k], atta);
  }

  if (l < nrows) {
    float* grow = g + (gbase + row0 + l) * 128 + c0;
#pragma unroll
    for (int cc = 0; cc < 4; ++cc)
      ((float4*)grow)[cc] = make_float4(acc[cc*4], acc[cc*4+1], acc[cc*4+2], acc[cc*4+3]);
    if (w == 0) LS[gbase + row0 + l] = atta;
    if (w == 1) LD[gbase + row0 + l] = atta;
  }
}

// ---------------- edge softmax + aggregate + GRU update (fused) ----------------
// UNCHANGED from R4 (single-variable experiment). wave per (b,node), lane = channel
// pair {l, 64+l}; 4-wide pipelined gather over 512B-aligned g rows; logits L2-hot.
__global__ __launch_bounds__(256) void edge_step(
    const float* __restrict__ g, const float* __restrict__ LS, const float* __restrict__ LD,
    const int* __restrict__ off, const int* __restrict__ csr,
    const float* __restrict__ bias, float* __restrict__ h, float* __restrict__ yout)
{
  int w = threadIdx.x >> 6, l = threadIdx.x & 63;
  int b = blockIdx.x & 7;                       // batch -> XCD affinity
  int n = (blockIdx.x >> 3) * 4 + w;            // 0..4999
  int base = b * NNODE + n;
  const float* gb  = g  + (size_t)b * NNODE * 128;
  const float* LSb = LS + (size_t)b * NNODE;
  float ad = LD[base];
  size_t hidx = (size_t)base * 64 + l;
  float hp = h[hidx];                           // issue early; consumed only in epilogue
  int s0 = off[n], s1 = off[n + 1];

  // pass A: max of a_s over edges; LR applied once (exact, LR monotone)
  float ms = -1e30f;
  for (int jj = s0 + l; jj < s1; jj += 64) ms = fmaxf(ms, LSb[csr[jj]]);
#pragma unroll
  for (int o = 32; o; o >>= 1) ms = fmaxf(ms, __shfl_xor(ms, o));
  float me = ms + ad;
  float m = me > 0.f ? me : 0.2f * me;

  // pass B: 4-wide pipelined aggregate
  float den = 0.f, a0 = 0.f, a1 = 0.f;
  int last = s1 - 1;
  for (int jj = s0; jj < s1; jj += 4) {
    int i1 = jj + 1 > last ? last : jj + 1;
    int i2 = jj + 2 > last ? last : jj + 2;
    int i3 = jj + 3 > last ? last : jj + 3;
    int sA = csr[jj], sB = csr[i1], sC = csr[i2], sD = csr[i3];
    float lsA = LSb[sA], lsB = LSb[sB], lsC = LSb[sC], lsD = LSb[sD];
    const float* gA = gb + (size_t)sA * 128;
    const float* gB = gb + (size_t)sB * 128;
    const float* gC = gb + (size_t)sC * 128;
    const float* gD = gb + (size_t)sD * 128;
    float zA = gA[l], nA = gA[64 + l];
    float zB = gB[l], nB = gB[64 + l];
    float zC = gC[l], nC = gC[64 + l];
    float zD = gD[l], nD = gD[64 + l];
    float eA = lsA + ad; eA = eA > 0.f ? eA : 0.2f * eA;
    float eB = lsB + ad; eB = eB > 0.f ? eB : 0.2f * eB;
    float eC = lsC + ad; eC = eC > 0.f ? eC : 0.2f * eC;
    float eD = lsD + ad; eD = eD > 0.f ? eD : 0.2f * eD;
    float alA = __expf(eA - m);
    float alB = (jj + 1 <= last) ? __expf(eB - m) : 0.f;
    float alC = (jj + 2 <= last) ? __expf(eC - m) : 0.f;
    float alD = (jj + 3 <= last) ? __expf(eD - m) : 0.f;
    den += (alA + alB) + (alC + alD);
    a0 = fmaf(alA, zA, a0); a0 = fmaf(alB, zB, a0);
    a0 = fmaf(alC, zC, a0); a0 = fmaf(alD, zD, a0);
    a1 = fmaf(alA, nA, a1); a1 = fmaf(alB, nB, a1);
    a1 = fmaf(alC, nC, a1); a1 = fmaf(alD, nD, a1);
  }

  // fused GRU pointwise
  float inv = 1.0f / den;
  float zx = fmaf(a0, inv, bias[64 + l]);
  float z = 1.0f / (1.0f + __expf(-zx));
  float nx = fmaf(a1, inv, bias[128 + l]);
  float e2 = __expf(2.0f * nx);
  float nn = 1.0f - 2.0f / (e2 + 1.0f);
  float hn = (1.0f - z) * nn + z * hp;
  h[hidx] = hn;
  yout[hidx] = hn;
}

// ---------------- host ----------------
extern "C" void kernel_launch(void* const* d_in, const int* in_sizes, int n_in,
                              void* d_out, int out_size, void* d_ws, size_t ws_size,
                              hipStream_t stream)
{
  const float* x   = (const float*)d_in[0];
  const void*  ei  = d_in[1];
  const float* W0  = (const float*)d_in[2];
  const float* as0 = (const float*)d_in[3];
  const float* ad0 = (const float*)d_in[4];
  const float* b0  = (const float*)d_in[5];
  const float* W1  = (const float*)d_in[6];
  const float* as1 = (const float*)d_in[7];
  const float* ad1 = (const float*)d_in[8];
  const float* b1  = (const float*)d_in[9];
  float* out = (float*)d_out;

  float* ws   = (float*)d_ws;
  float* Wc0  = ws;                              // 128*128
  float* Was0 = Wc0 + 128 * 128;                 // 128
  float* Wad0 = Was0 + 128;                      // 128
  float* Wc1  = Wad0 + 128;
  float* Was1 = Wc1 + 128 * 128;
  float* Wad1 = Was1 + 128;
  float* g    = Wad1 + 128;                      // MM*128 (512B-aligned rows)
  float* LS   = g + (size_t)MM * 128;            // MM
  float* LD   = LS + MM;                         // MM
  float* h    = LD + MM;                         // MM*64
  int* ib     = (int*)(h + (size_t)MM * 64);
  int* flag   = ib;                              // 16
  int* es     = ib + 16;                         // EE
  int* ed     = es + EE;                         // EE
  int* counts = ed + EE;                         // 5008
  int* off    = counts + 5008;                   // 5008
  int* cursor = off + 5008;                      // 5008
  int* csr    = cursor + 5008;                   // EE+NNODE

  detect_k<<<1, 64, 0, stream>>>((const unsigned*)ei, flag);
  normalize_k<<<(EE + 255) / 256, 256, 0, stream>>>(ei, flag, es, ed);
  prep_w<<<1, 128, 0, stream>>>(W0, as0, ad0, Wc0, Was0, Wad0);
  prep_w<<<1, 128, 0, stream>>>(W1, as1, ad1, Wc1, Was1, Wad1);
  init_counts<<<(NNODE + 255) / 256, 256, 0, stream>>>(counts);
  count_edges<<<(EE + 255) / 256, 256, 0, stream>>>(es, ed, counts);
  scan_k<<<1, 1024, 0, stream>>>(counts, off, cursor);
  scatter_k<<<(EE + NNODE + 255) / 256, 256, 0, stream>>>(es, ed, cursor, csr);

  size_t slab = (size_t)MM * 64;
  const int GB = 79 * 8;                         // gemm blocks: 64 rows each

  hipMemsetAsync(h, 0, slab * sizeof(float), stream);
  for (int t = 0; t < TT; ++t) {
    gemm_step<<<GB, 512, 0, stream>>>(x + (size_t)t * slab, h, Wc0, Was0, Wad0, g, LS, LD);
    edge_step<<<10000, 256, 0, stream>>>(g, LS, LD, off, csr, b0, h, out + (size_t)t * slab);
  }

  hipMemsetAsync(h, 0, slab * sizeof(float), stream);
  float* out1 = out + (size_t)TT * slab;
  for (int t = 0; t < TT; ++t) {
    gemm_step<<<GB, 512, 0, stream>>>(out + (size_t)t * slab, h, Wc1, Was1, Wad1, g, LS, LD);
    edge_step<<<10000, 256, 0, stream>>>(g, LS, LD, off, csr, b1, h, out1 + (size_t)t * slab);
  }
}